// Round 17
// baseline (326.988 us; speedup 1.0000x reference)
//
#include <hip/hip_runtime.h>
#include <stdint.h>

// ---------------------------------------------------------------------------
// Fused wavelet window-attention v4: window-half split, 4 blocks/CU.
//   Block = 512 thr: one (unit, quarter); phases process 8 of 16 windows.
//   LDS 40KB = slab0/slab1 (2 bands, 16KB) + qk 24KB.
//     qk granule(G,np,Wl) 16B at u16 idx G*128 + np*64 + Wl*8 (Wl 0..7).
//     mid: Q G0-31 | K 32-63 | V 64-95 (24KB). low [0:6144) / high [6144:12288):
//     each Q G0-15 | K 16-31 | V 32-47.
//   DWT runs twice (A1: lh,hl for mid; A2: ll,hh for low/high) -- x re-read
//   is L3-resident. y parks in GLOBAL scratch (uint4, 32KB/block), readback
//   in 2 W-half rounds through ot (38KB, overlays smem).
//   No value crosses a barrier in registers (W-split, not d-split).
// ---------------------------------------------------------------------------

typedef _Float16 halfT;
typedef __attribute__((ext_vector_type(2))) _Float16 half2T;
typedef __attribute__((ext_vector_type(8))) _Float16 half8;
typedef __attribute__((ext_vector_type(4))) float f32x4;

union H8 { half8 v; half2T h2[4]; uint16_t s[8]; };
union H2U { half2T h; uint32_t u; };

static __device__ __forceinline__ uint16_t f2h(float f){
  union { halfT h; uint16_t u; } x; x.h = (halfT)f; return x.u;
}
static __device__ __forceinline__ float h2f(uint16_t u){
  union { uint16_t u; halfT h; } x; x.u = u; return (float)x.h;
}
static __device__ __forceinline__ float dot4(half2T a0, half2T a1,
                                             half2T b0, half2T b1){
#if __has_builtin(__builtin_amdgcn_fdot2)
  return __builtin_amdgcn_fdot2(a1, b1, __builtin_amdgcn_fdot2(a0, b0, 0.f, false), false);
#else
  half2T p = a0*b0 + a1*b1;
  return (float)p.x + (float)p.y;
#endif
}
static __device__ __forceinline__ half2T pk2(float e){
#if __has_builtin(__builtin_amdgcn_cvt_pkrtz)
  union { __fp16 __attribute__((ext_vector_type(2))) p; half2T h; } c;
  c.p = __builtin_amdgcn_cvt_pkrtz(e, e);
  return c.h;
#else
  half2T r; r.x = (halfT)e; r.y = (halfT)e; return r;
#endif
}

__global__ void k_wt(const float* __restrict__ wlh, const float* __restrict__ wm,
                     halfT* __restrict__ wH){
  int i = blockIdx.x * 256 + threadIdx.x;
  if (i < 12288)      wH[i] = (halfT)wlh[i];
  else if (i < 61440) wH[i] = (halfT)wm[i - 12288];
}

// exp2-folded scales: scale * log2(e)
#define SC_LH 0.36067376022224085f
#define SC_M  0.25506120808935443f

// one ch-pair (2 rows, fdot2-paired), D iters; writes packed y as one uint4
template<int D>
static __device__ __forceinline__ void attn_core(const uint16_t* __restrict__ qb_,
    const uint16_t* __restrict__ kb_, const uint16_t* __restrict__ vb_,
    float sc, uint4* __restrict__ dst){
  const halfT sh = (halfT)sc;
  const half8 s8 = {sh,sh,sh,sh,sh,sh,sh,sh};
  H8 qg; qg.v = (*(const half8*)qb_) * s8;
  float sum0 = 0.f, sum1 = 0.f;
  half2T A0 = {(halfT)0,(halfT)0}, A1 = A0, B0 = A0, B1 = A0;
  #pragma unroll
  for (int d = 0; d < D; ++d){
    H8 kg, vg;
    kg.v = *(const half8*)&kb_[d*128];
    vg.v = *(const half8*)&vb_[d*128];
    float a0 = dot4(qg.h2[0], qg.h2[1], kg.h2[0], kg.h2[1]);
    float a1 = dot4(qg.h2[2], qg.h2[3], kg.h2[2], kg.h2[3]);
    float e0 = exp2f(a0), e1 = exp2f(a1);
    sum0 += e0; sum1 += e1;
    half2T p0 = pk2(e0), p1 = pk2(e1);
    A0 += p0*vg.h2[0]; A1 += p0*vg.h2[1];
    B0 += p1*vg.h2[2]; B1 += p1*vg.h2[3];
  }
  halfT i0 = (halfT)__builtin_amdgcn_rcpf(sum0);
  halfT i1 = (halfT)__builtin_amdgcn_rcpf(sum1);
  half2T v0 = {i0,i0}, v1 = {i1,i1};
  H2U u0, u1, u2, u3;
  u0.h = A0*v0; u1.h = A1*v0; u2.h = B0*v1; u3.h = B1*v1;
  uint4 r; r.x = u0.u; r.y = u1.u; r.z = u2.u; r.w = u3.u;
  *dst = r;
}

// K=64 conv (low/high): 12 M-tiles over 4 ms-splits of 3
static __device__ __forceinline__ void conv64v(const halfT* __restrict__ w,
    const uint16_t* __restrict__ slab, uint16_t* __restrict__ qs,
    int mrow, int g, int ms, int pxb, int wbq){
  half8 bfr[2];
  #pragma unroll
  for (int ks = 0; ks < 2; ++ks){
    H8 t; int cb = ks*32 + g*8;
    #pragma unroll
    for (int k = 0; k < 8; ++k)
      t.s[k] = slab[(cb + k)*64 + (pxb ^ (g << 4))];
    bfr[ks] = t.v;
  }
  #pragma unroll
  for (int mi = 0; mi < 3; ++mi){
    int mt = ms*3 + mi;
    f32x4 acc = {0.f,0.f,0.f,0.f};
    #pragma unroll
    for (int ks = 0; ks < 2; ++ks){
      half8 a = *(const half8*)&w[(mt*16 + mrow)*64 + ks*32 + g*8];
      acc = __builtin_amdgcn_mfma_f32_16x16x32_f16(a, bfr[ks], acc, 0, 0, 0);
    }
    uint16_t* wp = qs + (mt*4 + g)*128 + wbq;
    wp[0]  = f2h(acc[0]); wp[4]  = f2h(acc[1]);
    wp[64] = f2h(acc[2]); wp[68] = f2h(acc[3]);
  }
}

// DWT pass: BSEL 0 -> write lh,hl; BSEL 1 -> write ll,hh
template<int BSEL>
static __device__ __forceinline__ void dwt_pass(const float* __restrict__ xb,
    int hw, int col0, int tid, uint16_t* __restrict__ s0,
    uint16_t* __restrict__ s1){
  #pragma unroll
  for (int it = 0; it < 4; ++it){
    int idx = it*512 + tid;
    int j = idx & 15, rp = (idx >> 4) & 1, c = idx >> 5;
    const float* src = xb + (size_t)c*65536 + (size_t)(4*hw + 2*rp)*256 + col0 + 4*j;
    float4 r0 = *(const float4*)src;
    float4 r1 = *(const float4*)(src + 256);
    int base = c*64 + ((rp*32 + 2*j) ^ (((c >> 3) & 3) << 4));
    if (BSEL == 0){
      float a0 = 0.5f*(-r0.x - r0.y + r1.x + r1.y);
      float a1 = 0.5f*(-r0.z - r0.w + r1.z + r1.w);
      float b0 = 0.5f*(-r0.x + r0.y - r1.x + r1.y);
      float b1 = 0.5f*(-r0.z + r0.w - r1.z + r1.w);
      *(uint32_t*)&s0[base] = (uint32_t)f2h(a0) | ((uint32_t)f2h(a1) << 16);
      *(uint32_t*)&s1[base] = (uint32_t)f2h(b0) | ((uint32_t)f2h(b1) << 16);
    } else {
      float a0 = 0.5f*( r0.x + r0.y + r1.x + r1.y);
      float a1 = 0.5f*( r0.z + r0.w + r1.z + r1.w);
      float b0 = 0.5f*( r0.x - r0.y - r1.x + r1.y);
      float b1 = 0.5f*( r0.z - r0.w - r1.z + r1.w);
      *(uint32_t*)&s0[base] = (uint32_t)f2h(a0) | ((uint32_t)f2h(a1) << 16);
      *(uint32_t*)&s1[base] = (uint32_t)f2h(b0) | ((uint32_t)f2h(b1) << 16);
    }
  }
}

__global__ __launch_bounds__(512, 8) void k_fused(const float* __restrict__ x,
    const halfT* __restrict__ wH, float* __restrict__ out,
    uint32_t* __restrict__ yg0, int u0){
  __shared__ __align__(16) uint8_t smem[40960];
  uint16_t* slab0 = (uint16_t*)smem;            // 8KB
  uint16_t* slab1 = (uint16_t*)(smem + 8192);   // 8KB
  uint16_t* qk    = (uint16_t*)(smem + 16384);  // 24KB
  float*    ot    = (float*)smem;               // readback reuse

  const int tid = threadIdx.x;
  const int wv = tid >> 6, lane = tid & 63;
  const int blk = blockIdx.x;
  const int unit = u0 + (blk >> 2), q4 = blk & 3;
  const int b = unit >> 6, hw = unit & 63;
  const int col0 = q4 * 64;
  const float* xb = x + (size_t)b * 64 * 65536;
  const halfT* wM = wH + 12288;
  uint32_t* yg = yg0 + (size_t)blk * 8192;      // 32KB scratch per block

  // conv thread indices: nt = N-tile (row-pair), ms = M-split
  const int mrow = lane & 15, g = lane >> 4;
  const int nt = wv & 1, ms = wv >> 1;
  const int wbq = ((mrow >> 1) << 3) + nt*2 + (mrow & 1);  // Wl*8 + q
  const int pxb0 = nt*32 + mrow;                           // wh=0 cols 0..15
  const int pxb1 = nt*32 + 16 + mrow;                      // wh=1 cols 16..31

  // attn thread indices: wave = Wl, lane = (hi5: path/side, li: G,np)
  const int li = lane & 31, hi5 = lane >> 5;
  const int aoff = (li & 1)*64 + wv*8;          // np*64 + Wl*8

  // ---------------- A1: DWT -> lh (slab0), hl (slab1) ----------------
  dwt_pass<0>(xb, hw, col0, tid, slab0, slab1);
  __syncthreads();                                        // b1

  // ---------------- mid path, two window-halves ----------------
  #pragma unroll 1
  for (int wh = 0; wh < 2; ++wh){
    { // convM: K=128 from slab0(lh)+slab1(hl); 24 mt over 4 ms-splits of 6
      int pxb = wh ? pxb1 : pxb0;
      half8 bfr[4];
      #pragma unroll
      for (int ks = 0; ks < 4; ++ks){
        const uint16_t* sl = (ks < 2) ? slab0 : slab1;
        H8 t; int cb = (ks & 1)*32 + g*8;
        #pragma unroll
        for (int k = 0; k < 8; ++k)
          t.s[k] = sl[(cb + k)*64 + (pxb ^ (g << 4))];
        bfr[ks] = t.v;
      }
      #pragma unroll
      for (int mi = 0; mi < 6; ++mi){
        int mt = ms*6 + mi;
        f32x4 acc = {0.f,0.f,0.f,0.f};
        #pragma unroll
        for (int ks = 0; ks < 4; ++ks){
          half8 a = *(const half8*)&wM[(mt*16 + mrow)*128 + ks*32 + g*8];
          acc = __builtin_amdgcn_mfma_f32_16x16x32_f16(a, bfr[ks], acc, 0, 0, 0);
        }
        uint16_t* wp = qk + (mt*4 + g)*128 + wbq;
        wp[0]  = f2h(acc[0]); wp[4]  = f2h(acc[1]);
        wp[64] = f2h(acc[2]); wp[68] = f2h(acc[3]);
      }
    }
    __syncthreads();                                      // b2 / b4
    { // attnM: side = hi5 (0 lh-rows, 1 hl-rows); Wg = wh*8 + wv
      if (wh == 1) dwt_pass<1>(xb, hw, col0, tid, slab0, slab1);  // A2 overlap
      int Gq = hi5*16 + (li >> 1);
      int Wg = wh*8 + wv;
      attn_core<32>(qk + Gq*128 + aoff, qk + 4096 + aoff, qk + 8192 + aoff,
                    SC_M, (uint4*)(yg + ((1 + hi5)*16 + Wg)*128) + li);
    }
    __syncthreads();                                      // b3 / b5
  }

  // ---------------- low+high paths, two window-halves ----------------
  #pragma unroll 1
  for (int wh = 0; wh < 2; ++wh){
    {
      int pxb = wh ? pxb1 : pxb0;
      conv64v(wH, slab0, qk,        mrow, g, ms, pxb, wbq);   // low (ll)
      conv64v(wH, slab1, qk + 6144, mrow, g, ms, pxb, wbq);   // high (hh)
    }
    __syncthreads();                                      // b6 / b8
    { // attnLH: path = hi5 (0 low -> p0, 1 high -> p3)
      const uint16_t* qs = qk + hi5*6144;
      int Wg = wh*8 + wv;
      attn_core<16>(qs + (li >> 1)*128 + aoff, qs + 2048 + aoff,
                    qs + 4096 + aoff, SC_LH,
                    (uint4*)(yg + ((hi5 ? 3 : 0)*16 + Wg)*128) + li);
    }
    __syncthreads();                                      // b7 / b9
  }

  // ---------------- readback + iDWT + store, 2 W-half rounds -------------
  #pragma unroll 1
  for (int r = 0; r < 2; ++r){
    if ((wv >> 2) == r){
      int aw = wv & 3;
      int W = r*8 + aw*2 + hi5;
      int m = li;
      uint4 yq[4];
      #pragma unroll
      for (int p = 0; p < 4; ++p)
        yq[p] = *((const uint4*)(yg + (p*16 + W)*128) + m);
      int lc = (W & 7)*4;
      #pragma unroll
      for (int chi = 0; chi < 2; ++chi){
        float ya[4][4];
        #pragma unroll
        for (int p = 0; p < 4; ++p){
          uint32_t lo = chi ? yq[p].z : yq[p].x;
          uint32_t hi_ = chi ? yq[p].w : yq[p].y;
          ya[p][0] = h2f((uint16_t)(lo & 0xffffu));
          ya[p][1] = h2f((uint16_t)(lo >> 16));
          ya[p][2] = h2f((uint16_t)(hi_ & 0xffffu));
          ya[p][3] = h2f((uint16_t)(hi_ >> 16));
        }
        float* otc = ot + (2*m + chi)*148 + lc;
        #pragma unroll
        for (int rp = 0; rp < 2; ++rp){
          float4 top, bot;
          #pragma unroll
          for (int cp = 0; cp < 2; ++cp){
            int s2 = rp*2 + cp;
            float ll = ya[0][s2], lh = ya[1][s2];
            float hl = ya[2][s2], hh = ya[3][s2];
            float va = 0.5f*(ll - lh - hl + hh);
            float vb = 0.5f*(ll - lh + hl - hh);
            float vc = 0.5f*(ll + lh - hl - hh);
            float vd = 0.5f*(ll + lh + hl + hh);
            if (cp == 0){ top.x = va; top.y = vb; bot.x = vc; bot.y = vd; }
            else        { top.z = va; top.w = vb; bot.z = vc; bot.w = vd; }
          }
          *(float4*)&otc[(2*rp)*36]   = top;
          *(float4*)&otc[(2*rp+1)*36] = bot;
        }
      }
    }
    __syncthreads();
    { // coalesced store of this 32-col half
      int ch = tid >> 3, row = (tid >> 1) & 3, seg = tid & 1;
      const float* rowp = ot + ch*148 + row*36 + seg*16;
      float4 v0 = *(const float4*)(rowp + 0);
      float4 v1 = *(const float4*)(rowp + 4);
      float4 v2 = *(const float4*)(rowp + 8);
      float4 v3 = *(const float4*)(rowp + 12);
      float* dst = out + (((size_t)b*64 + ch)*256 + (size_t)(4*hw + row))*256
                 + col0 + r*32 + seg*16;
      ((float4*)dst)[0] = v0; ((float4*)dst)[1] = v1;
      ((float4*)dst)[2] = v2; ((float4*)dst)[3] = v3;
    }
    __syncthreads();
  }
}

// ---------------------------------------------------------------------------
extern "C" void kernel_launch(void* const* d_in, const int* in_sizes, int n_in,
                              void* d_out, int out_size, void* d_ws, size_t ws_size,
                              hipStream_t stream){
  const float* x   = (const float*)d_in[0];
  const float* wlh = (const float*)d_in[1];
  const float* wm  = (const float*)d_in[2];
  float* out = (float*)d_out;
  halfT* wHp = (halfT*)d_ws;                         // 122880 B
  uint32_t* yg = (uint32_t*)((char*)d_ws + 122880);  // y scratch

  hipLaunchKernelGGL(k_wt, dim3(240), dim3(256), 0, stream, wlh, wm, wHp);

  size_t avail = (ws_size > 122880) ? ws_size - 122880 : 0;
  long long U = (long long)(avail / 131072ULL);      // 4 blocks * 32KB per unit
  if (U < 1)   U = 1;
  if (U > 512) U = 512;
  for (int u0 = 0; u0 < 512; u0 += (int)U){
    int Uc = (512 - u0 < (int)U) ? (512 - u0) : (int)U;
    hipLaunchKernelGGL(k_fused, dim3(Uc*4), dim3(512), 0, stream,
                       x, wHp, out, yg, u0);
  }
}

// Round 18
// 180.073 us; speedup vs baseline: 1.8159x; 1.8159x over previous
//
#include <hip/hip_runtime.h>
#include <stdint.h>

// ---------------------------------------------------------------------------
// Fused wavelet window-attention v5: 32-col blocks, 4 blocks/CU (100% waves).
//   Block = 512 thr: (unit, 32 orig cols) = 2 half-rows x 16 half-cols, 8 win.
//   LDS 40960B EXACT = bands[4][c64][px32] (16KB, swz px^(((c>>3)&3)<<3))
//                    + qk 24KB: granule(G,np,Wl) = G*128+np*64+Wl*8+e*4+q u16.
//     low qk[0:6144) | high [6144:12288) co-resident; mid full [0:12288).
//   y per path = 4KB = one dead band slab (R11 parking, no global scratch).
//   conv px = 2*mrow+nt -> write banks spread 16 (4-way, was 8-way).
//   Phases: DWT |b1| convL+convH |b2| attnLH |b3| convM |b4| attnM |b5|
//           y-readback |b6| iDWT->ot(32KB overlay) |b7| store.
//   R17 lesson: occupancy must not cost HBM traffic (x read once, y in LDS).
// ---------------------------------------------------------------------------

typedef _Float16 halfT;
typedef __attribute__((ext_vector_type(2))) _Float16 half2T;
typedef __attribute__((ext_vector_type(8))) _Float16 half8;
typedef __attribute__((ext_vector_type(4))) float f32x4;

union H8 { half8 v; half2T h2[4]; uint16_t s[8]; };
union H2U { half2T h; uint32_t u; };

static __device__ __forceinline__ uint16_t f2h(float f){
  union { halfT h; uint16_t u; } x; x.h = (halfT)f; return x.u;
}
static __device__ __forceinline__ float h2f(uint16_t u){
  union { uint16_t u; halfT h; } x; x.u = u; return (float)x.h;
}
static __device__ __forceinline__ float dot4(half2T a0, half2T a1,
                                             half2T b0, half2T b1){
#if __has_builtin(__builtin_amdgcn_fdot2)
  return __builtin_amdgcn_fdot2(a1, b1, __builtin_amdgcn_fdot2(a0, b0, 0.f, false), false);
#else
  half2T p = a0*b0 + a1*b1;
  return (float)p.x + (float)p.y;
#endif
}
static __device__ __forceinline__ half2T pk2(float e){
#if __has_builtin(__builtin_amdgcn_cvt_pkrtz)
  union { __fp16 __attribute__((ext_vector_type(2))) p; half2T h; } c;
  c.p = __builtin_amdgcn_cvt_pkrtz(e, e);
  return c.h;
#else
  half2T r; r.x = (halfT)e; r.y = (halfT)e; return r;
#endif
}

__global__ void k_wt(const float* __restrict__ wlh, const float* __restrict__ wm,
                     halfT* __restrict__ wH){
  int i = blockIdx.x * 256 + threadIdx.x;
  if (i < 12288)      wH[i] = (halfT)wlh[i];
  else if (i < 61440) wH[i] = (halfT)wm[i - 12288];
}

// exp2-folded scales: scale * log2(e)
#define SC_LH 0.36067376022224085f
#define SC_M  0.25506120808935443f

// one ch-pair, D iters (K/V granule stride 128 u16); writes uint4 y
template<int D>
static __device__ __forceinline__ void attn_core(const uint16_t* __restrict__ qb_,
    const uint16_t* __restrict__ kb_, const uint16_t* __restrict__ vb_,
    float sc, uint4* __restrict__ dst){
  const halfT sh = (halfT)sc;
  const half8 s8 = {sh,sh,sh,sh,sh,sh,sh,sh};
  H8 qg; qg.v = (*(const half8*)qb_) * s8;
  float sum0 = 0.f, sum1 = 0.f;
  half2T A0 = {(halfT)0,(halfT)0}, A1 = A0, B0 = A0, B1 = A0;
  #pragma unroll
  for (int d = 0; d < D; ++d){
    H8 kg, vg;
    kg.v = *(const half8*)&kb_[d*128];
    vg.v = *(const half8*)&vb_[d*128];
    float a0 = dot4(qg.h2[0], qg.h2[1], kg.h2[0], kg.h2[1]);
    float a1 = dot4(qg.h2[2], qg.h2[3], kg.h2[2], kg.h2[3]);
    float e0 = exp2f(a0), e1 = exp2f(a1);
    sum0 += e0; sum1 += e1;
    half2T p0 = pk2(e0), p1 = pk2(e1);
    A0 += p0*vg.h2[0]; A1 += p0*vg.h2[1];
    B0 += p1*vg.h2[2]; B1 += p1*vg.h2[3];
  }
  halfT i0 = (halfT)__builtin_amdgcn_rcpf(sum0);
  halfT i1 = (halfT)__builtin_amdgcn_rcpf(sum1);
  half2T v0 = {i0,i0}, v1 = {i1,i1};
  H2U u0, u1, u2, u3;
  u0.h = A0*v0; u1.h = A1*v0; u2.h = B0*v1; u3.h = B1*v1;
  uint4 r; r.x = u0.u; r.y = u1.u; r.z = u2.u; r.w = u3.u;
  *dst = r;
}

// K=64 conv: 12 M-tiles over ms(4) splits of 3; writes granule layout
static __device__ __forceinline__ void conv64v(const halfT* __restrict__ w,
    const uint16_t* __restrict__ bands, uint16_t* __restrict__ qs,
    int band, int mrow, int g, int ms, int px, int qoff){
  half8 bfr[2];
  #pragma unroll
  for (int ks = 0; ks < 2; ++ks){
    H8 t; int cb = ks*32 + g*8;
    #pragma unroll
    for (int k = 0; k < 8; ++k)
      t.s[k] = bands[band*2048 + (cb + k)*32 + (px ^ (g << 3))];
    bfr[ks] = t.v;
  }
  #pragma unroll
  for (int mi = 0; mi < 3; ++mi){
    int mt = ms*3 + mi;
    f32x4 acc = {0.f,0.f,0.f,0.f};
    #pragma unroll
    for (int ks = 0; ks < 2; ++ks){
      half8 a = *(const half8*)&w[(mt*16 + mrow)*64 + ks*32 + g*8];
      acc = __builtin_amdgcn_mfma_f32_16x16x32_f16(a, bfr[ks], acc, 0, 0, 0);
    }
    uint16_t* wp = qs + (mt*4 + g)*128 + qoff;
    wp[0]  = f2h(acc[0]); wp[4]  = f2h(acc[1]);
    wp[64] = f2h(acc[2]); wp[68] = f2h(acc[3]);
  }
}

__global__ __launch_bounds__(512, 8) void k_fused(const float* __restrict__ x,
    const halfT* __restrict__ wH, float* __restrict__ out){
  __shared__ __align__(16) uint8_t smem[40960];
  uint16_t* bands = (uint16_t*)smem;                 // 16384 B (4 slabs x 4KB)
  uint16_t* qk    = (uint16_t*)(smem + 16384);       // 24576 B
  uint32_t* ybuf  = (uint32_t*)smem;                 // y slabs (dead bands)
  float*    ot    = (float*)smem;                    // 32KB overlay at end

  const int tid = threadIdx.x;
  const int wv = tid >> 6, lane = tid & 63;
  const int blk = blockIdx.x;
  const int unit = blk >> 3, cg = blk & 7;
  const int b = unit >> 6, hw = unit & 63;
  const int col0 = cg * 32;
  const float* xb = x + (size_t)b * 64 * 65536;
  const halfT* wM = wH + 12288;

  // ---------------- phase A: load x + Haar DWT -> bands -------------------
  #pragma unroll
  for (int it = 0; it < 2; ++it){
    int idx = it*512 + tid;
    int j = idx & 7, rp = (idx >> 3) & 1, c = idx >> 4;   // c 0..63
    const float* src = xb + (size_t)c*65536 + (size_t)(4*hw + 2*rp)*256 + col0 + 4*j;
    float4 r0 = *(const float4*)src;
    float4 r1 = *(const float4*)(src + 256);
    float v0[4], v1[4];
    v0[0] = 0.5f*( r0.x + r0.y + r1.x + r1.y);
    v0[1] = 0.5f*(-r0.x - r0.y + r1.x + r1.y);
    v0[2] = 0.5f*(-r0.x + r0.y - r1.x + r1.y);
    v0[3] = 0.5f*( r0.x - r0.y - r1.x + r1.y);
    v1[0] = 0.5f*( r0.z + r0.w + r1.z + r1.w);
    v1[1] = 0.5f*(-r0.z - r0.w + r1.z + r1.w);
    v1[2] = 0.5f*(-r0.z + r0.w - r1.z + r1.w);
    v1[3] = 0.5f*( r0.z - r0.w - r1.z + r1.w);
    int px0 = rp*16 + 2*j;
    int base = (c*32 + (px0 ^ (((c >> 3) & 3) << 3))) >> 1;   // u32 index
    #pragma unroll
    for (int bb = 0; bb < 4; ++bb)
      ybuf[bb*1024 + base] = (uint32_t)f2h(v0[bb]) | ((uint32_t)f2h(v1[bb]) << 16);
  }
  __syncthreads();                                   // b1

  // conv indices
  const int mrow = lane & 15, g = lane >> 4;
  const int nt = wv >> 2, ms = wv & 3;
  const int px = 2*mrow + nt;                        // column permutation
  const int Wl = mrow & 7;
  const int qq = (mrow >> 3)*2 + nt;
  const int qoff = Wl*8 + qq;
  // attn indices
  const int li = lane & 31, hi5 = lane >> 5;

  // ---- phase B: convL + convH (co-resident qk halves) --------------------
  conv64v(wH, bands, qk,        0, mrow, g, ms, px, qoff);   // low  (ll)
  conv64v(wH, bands, qk + 6144, 3, mrow, g, ms, px, qoff);   // high (hh)
  __syncthreads();                                   // b2

  // ---- phase C: attnLH -> park y0 (band0), y3 (band3) --------------------
  {
    const uint16_t* qs = qk + hi5*6144;
    int aoff = (li & 1)*64 + wv*8;                   // np*64 + W*8
    attn_core<16>(qs + (li >> 1)*128 + aoff, qs + 2048 + aoff, qs + 4096 + aoff,
                  SC_LH, (uint4*)(ybuf + (hi5 ? 3 : 0)*1024 + wv*128) + li);
  }
  __syncthreads();                                   // b3

  // ---- phase D: convM (full qk), K=128 from bands 1,2 --------------------
  {
    half8 bfr[4];
    #pragma unroll
    for (int ks = 0; ks < 4; ++ks){
      H8 t; int band = 1 + (ks >> 1); int cb = (ks & 1)*32 + g*8;
      #pragma unroll
      for (int k = 0; k < 8; ++k)
        t.s[k] = bands[band*2048 + (cb + k)*32 + (px ^ (g << 3))];
      bfr[ks] = t.v;
    }
    #pragma unroll
    for (int mi = 0; mi < 6; ++mi){
      int mt = ms*6 + mi;
      f32x4 acc = {0.f,0.f,0.f,0.f};
      #pragma unroll
      for (int ks = 0; ks < 4; ++ks){
        half8 a = *(const half8*)&wM[(mt*16 + mrow)*128 + ks*32 + g*8];
        acc = __builtin_amdgcn_mfma_f32_16x16x32_f16(a, bfr[ks], acc, 0, 0, 0);
      }
      uint16_t* wp = qk + (mt*4 + g)*128 + qoff;     // G = mt*4+g 0..95
      wp[0]  = f2h(acc[0]); wp[4]  = f2h(acc[1]);
      wp[64] = f2h(acc[2]); wp[68] = f2h(acc[3]);
    }
  }
  __syncthreads();                                   // b4

  // ---- phase E: attnM -> park y1 (band1), y2 (band2) ---------------------
  {
    int m = lane;                                    // chpair 0..63
    int aoff = (m & 1)*64 + wv*8;
    attn_core<32>(qk + (m >> 1)*128 + aoff, qk + 4096 + aoff, qk + 8192 + aoff,
                  SC_M, (uint4*)(ybuf + (m < 32 ? 1 : 2)*1024 + wv*128) + (m & 31));
  }
  __syncthreads();                                   // b5

  // ---- phase F: y readback (cross-thread) --------------------------------
  float ya[4][4];
  {
    int chi = tid & 1, m = (tid >> 1) & 31, W = tid >> 6;
    #pragma unroll
    for (int p = 0; p < 4; ++p){
      uint32_t lo = ybuf[p*1024 + W*128 + m*4 + chi*2];
      uint32_t hi_ = ybuf[p*1024 + W*128 + m*4 + chi*2 + 1];
      ya[p][0] = h2f((uint16_t)(lo & 0xffffu));
      ya[p][1] = h2f((uint16_t)(lo >> 16));
      ya[p][2] = h2f((uint16_t)(hi_ & 0xffffu));
      ya[p][3] = h2f((uint16_t)(hi_ >> 16));
    }
  }
  __syncthreads();                                   // b6

  // ---- phase G: iDWT in regs -> ot (32KB overlay) ------------------------
  {
    int chi = tid & 1, m = (tid >> 1) & 31, W = tid >> 6;
    int ch = 2*m + chi;
    float* otc = ot + ch*128 + ((W*4) ^ ((ch & 7) << 2));
    #pragma unroll
    for (int rp = 0; rp < 2; ++rp){
      float4 top, bot;
      #pragma unroll
      for (int cp = 0; cp < 2; ++cp){
        int s2 = rp*2 + cp;
        float ll = ya[0][s2], lh = ya[1][s2];
        float hl = ya[2][s2], hh = ya[3][s2];
        float va = 0.5f*(ll - lh - hl + hh);
        float vb = 0.5f*(ll - lh + hl - hh);
        float vc = 0.5f*(ll + lh - hl - hh);
        float vd = 0.5f*(ll + lh + hl + hh);
        if (cp == 0){ top.x = va; top.y = vb; bot.x = vc; bot.y = vd; }
        else        { top.z = va; top.w = vb; bot.z = vc; bot.w = vd; }
      }
      *(float4*)&otc[(2*rp)*32]   = top;
      *(float4*)&otc[(2*rp+1)*32] = bot;
    }
  }
  __syncthreads();                                   // b7

  // ---- phase H: coalesced store ------------------------------------------
  {
    int ch = tid >> 3, row = (tid >> 1) & 3, half = tid & 1;
    const float* rowp = ot + ch*128 + row*32;
    int sw = (ch & 7) << 2;
    float4 v0 = *(const float4*)&rowp[(half*16 + 0)  ^ sw];
    float4 v1 = *(const float4*)&rowp[(half*16 + 4)  ^ sw];
    float4 v2 = *(const float4*)&rowp[(half*16 + 8)  ^ sw];
    float4 v3 = *(const float4*)&rowp[(half*16 + 12) ^ sw];
    float* dst = out + (((size_t)b*64 + ch)*256 + (size_t)(4*hw + row))*256
               + col0 + half*16;
    ((float4*)dst)[0] = v0; ((float4*)dst)[1] = v1;
    ((float4*)dst)[2] = v2; ((float4*)dst)[3] = v3;
  }
}

// ---------------------------------------------------------------------------
extern "C" void kernel_launch(void* const* d_in, const int* in_sizes, int n_in,
                              void* d_out, int out_size, void* d_ws, size_t ws_size,
                              hipStream_t stream){
  const float* x   = (const float*)d_in[0];
  const float* wlh = (const float*)d_in[1];
  const float* wm  = (const float*)d_in[2];
  float* out = (float*)d_out;
  halfT* wHp = (halfT*)d_ws;               // 61440 f16 = 122880 B

  hipLaunchKernelGGL(k_wt,    dim3(240),  dim3(256), 0, stream, wlh, wm, wHp);
  hipLaunchKernelGGL(k_fused, dim3(4096), dim3(512), 0, stream, x, wHp, out);
}

// Round 19
// 178.110 us; speedup vs baseline: 1.8359x; 1.0110x over previous
//
#include <hip/hip_runtime.h>
#include <stdint.h>

// ---------------------------------------------------------------------------
// Fused wavelet window-attention v5.1: 32-col blocks, 4 blocks/CU,
// cross-barrier prefetch of convM B-fragments.
//   Block = 512 thr: (unit, 32 orig cols) = 2 half-rows x 16 half-cols, 8 win.
//   LDS 40960B EXACT = bands[4][c64][px32] (16KB, swz px^(((c>>3)&3)<<3))
//                    + qk 24KB: granule(G,np,Wl) = G*128+np*64+Wl*8+e*4+q u16.
//     low qk[0:6144) | high [6144:12288) co-resident; mid full [0:12288).
//   y per path = 4KB = one dead band slab (R11 parking, no global scratch).
//   Phases: DWT |b1| convL+convH |b2| [prefetch bfrM] attnLH |b3| convM |b4|
//           attnM |b5| y-readback |b6| iDWT->ot(32KB overlay) |b7| store.
//   R18 verified at 198us/78%occ; this adds only the bfrM hoist (phase D
//   opens with MFMAs instead of a 32-load LDS latency chain).
// ---------------------------------------------------------------------------

typedef _Float16 halfT;
typedef __attribute__((ext_vector_type(2))) _Float16 half2T;
typedef __attribute__((ext_vector_type(8))) _Float16 half8;
typedef __attribute__((ext_vector_type(4))) float f32x4;

union H8 { half8 v; half2T h2[4]; uint16_t s[8]; };
union H2U { half2T h; uint32_t u; };

static __device__ __forceinline__ uint16_t f2h(float f){
  union { halfT h; uint16_t u; } x; x.h = (halfT)f; return x.u;
}
static __device__ __forceinline__ float h2f(uint16_t u){
  union { uint16_t u; halfT h; } x; x.u = u; return (float)x.h;
}
static __device__ __forceinline__ float dot4(half2T a0, half2T a1,
                                             half2T b0, half2T b1){
#if __has_builtin(__builtin_amdgcn_fdot2)
  return __builtin_amdgcn_fdot2(a1, b1, __builtin_amdgcn_fdot2(a0, b0, 0.f, false), false);
#else
  half2T p = a0*b0 + a1*b1;
  return (float)p.x + (float)p.y;
#endif
}
static __device__ __forceinline__ half2T pk2(float e){
#if __has_builtin(__builtin_amdgcn_cvt_pkrtz)
  union { __fp16 __attribute__((ext_vector_type(2))) p; half2T h; } c;
  c.p = __builtin_amdgcn_cvt_pkrtz(e, e);
  return c.h;
#else
  half2T r; r.x = (halfT)e; r.y = (halfT)e; return r;
#endif
}

__global__ void k_wt(const float* __restrict__ wlh, const float* __restrict__ wm,
                     halfT* __restrict__ wH){
  int i = blockIdx.x * 256 + threadIdx.x;
  if (i < 12288)      wH[i] = (halfT)wlh[i];
  else if (i < 61440) wH[i] = (halfT)wm[i - 12288];
}

// exp2-folded scales: scale * log2(e)
#define SC_LH 0.36067376022224085f
#define SC_M  0.25506120808935443f

// one ch-pair, D iters (K/V granule stride 128 u16); writes uint4 y
template<int D>
static __device__ __forceinline__ void attn_core(const uint16_t* __restrict__ qb_,
    const uint16_t* __restrict__ kb_, const uint16_t* __restrict__ vb_,
    float sc, uint4* __restrict__ dst){
  const halfT sh = (halfT)sc;
  const half8 s8 = {sh,sh,sh,sh,sh,sh,sh,sh};
  H8 qg; qg.v = (*(const half8*)qb_) * s8;
  float sum0 = 0.f, sum1 = 0.f;
  half2T A0 = {(halfT)0,(halfT)0}, A1 = A0, B0 = A0, B1 = A0;
  #pragma unroll
  for (int d = 0; d < D; ++d){
    H8 kg, vg;
    kg.v = *(const half8*)&kb_[d*128];
    vg.v = *(const half8*)&vb_[d*128];
    float a0 = dot4(qg.h2[0], qg.h2[1], kg.h2[0], kg.h2[1]);
    float a1 = dot4(qg.h2[2], qg.h2[3], kg.h2[2], kg.h2[3]);
    float e0 = exp2f(a0), e1 = exp2f(a1);
    sum0 += e0; sum1 += e1;
    half2T p0 = pk2(e0), p1 = pk2(e1);
    A0 += p0*vg.h2[0]; A1 += p0*vg.h2[1];
    B0 += p1*vg.h2[2]; B1 += p1*vg.h2[3];
  }
  halfT i0 = (halfT)__builtin_amdgcn_rcpf(sum0);
  halfT i1 = (halfT)__builtin_amdgcn_rcpf(sum1);
  half2T v0 = {i0,i0}, v1 = {i1,i1};
  H2U u0, u1, u2, u3;
  u0.h = A0*v0; u1.h = A1*v0; u2.h = B0*v1; u3.h = B1*v1;
  uint4 r; r.x = u0.u; r.y = u1.u; r.z = u2.u; r.w = u3.u;
  *dst = r;
}

// K=64 conv: 12 M-tiles over ms(4) splits of 3; writes granule layout
static __device__ __forceinline__ void conv64v(const halfT* __restrict__ w,
    const uint16_t* __restrict__ bands, uint16_t* __restrict__ qs,
    int band, int mrow, int g, int ms, int px, int qoff){
  half8 bfr[2];
  #pragma unroll
  for (int ks = 0; ks < 2; ++ks){
    H8 t; int cb = ks*32 + g*8;
    #pragma unroll
    for (int k = 0; k < 8; ++k)
      t.s[k] = bands[band*2048 + (cb + k)*32 + (px ^ (g << 3))];
    bfr[ks] = t.v;
  }
  #pragma unroll
  for (int mi = 0; mi < 3; ++mi){
    int mt = ms*3 + mi;
    f32x4 acc = {0.f,0.f,0.f,0.f};
    #pragma unroll
    for (int ks = 0; ks < 2; ++ks){
      half8 a = *(const half8*)&w[(mt*16 + mrow)*64 + ks*32 + g*8];
      acc = __builtin_amdgcn_mfma_f32_16x16x32_f16(a, bfr[ks], acc, 0, 0, 0);
    }
    uint16_t* wp = qs + (mt*4 + g)*128 + qoff;
    wp[0]  = f2h(acc[0]); wp[4]  = f2h(acc[1]);
    wp[64] = f2h(acc[2]); wp[68] = f2h(acc[3]);
  }
}

__global__ __launch_bounds__(512, 8) void k_fused(const float* __restrict__ x,
    const halfT* __restrict__ wH, float* __restrict__ out){
  __shared__ __align__(16) uint8_t smem[40960];
  uint16_t* bands = (uint16_t*)smem;                 // 16384 B (4 slabs x 4KB)
  uint16_t* qk    = (uint16_t*)(smem + 16384);       // 24576 B
  uint32_t* ybuf  = (uint32_t*)smem;                 // y slabs (dead bands)
  float*    ot    = (float*)smem;                    // 32KB overlay at end

  const int tid = threadIdx.x;
  const int wv = tid >> 6, lane = tid & 63;
  const int blk = blockIdx.x;
  const int unit = blk >> 3, cg = blk & 7;
  const int b = unit >> 6, hw = unit & 63;
  const int col0 = cg * 32;
  const float* xb = x + (size_t)b * 64 * 65536;
  const halfT* wM = wH + 12288;

  // ---------------- phase A: load x + Haar DWT -> bands -------------------
  #pragma unroll
  for (int it = 0; it < 2; ++it){
    int idx = it*512 + tid;
    int j = idx & 7, rp = (idx >> 3) & 1, c = idx >> 4;   // c 0..63
    const float* src = xb + (size_t)c*65536 + (size_t)(4*hw + 2*rp)*256 + col0 + 4*j;
    float4 r0 = *(const float4*)src;
    float4 r1 = *(const float4*)(src + 256);
    float v0[4], v1[4];
    v0[0] = 0.5f*( r0.x + r0.y + r1.x + r1.y);
    v0[1] = 0.5f*(-r0.x - r0.y + r1.x + r1.y);
    v0[2] = 0.5f*(-r0.x + r0.y - r1.x + r1.y);
    v0[3] = 0.5f*( r0.x - r0.y - r1.x + r1.y);
    v1[0] = 0.5f*( r0.z + r0.w + r1.z + r1.w);
    v1[1] = 0.5f*(-r0.z - r0.w + r1.z + r1.w);
    v1[2] = 0.5f*(-r0.z + r0.w - r1.z + r1.w);
    v1[3] = 0.5f*( r0.z - r0.w - r1.z + r1.w);
    int px0 = rp*16 + 2*j;
    int base = (c*32 + (px0 ^ (((c >> 3) & 3) << 3))) >> 1;   // u32 index
    #pragma unroll
    for (int bb = 0; bb < 4; ++bb)
      ybuf[bb*1024 + base] = (uint32_t)f2h(v0[bb]) | ((uint32_t)f2h(v1[bb]) << 16);
  }
  __syncthreads();                                   // b1

  // conv indices
  const int mrow = lane & 15, g = lane >> 4;
  const int nt = wv >> 2, ms = wv & 3;
  const int px = 2*mrow + nt;                        // column permutation
  const int Wl = mrow & 7;
  const int qq = (mrow >> 3)*2 + nt;
  const int qoff = Wl*8 + qq;
  // attn indices
  const int li = lane & 31, hi5 = lane >> 5;

  // ---- phase B: convL + convH (co-resident qk halves) --------------------
  conv64v(wH, bands, qk,        0, mrow, g, ms, px, qoff);   // low  (ll)
  conv64v(wH, bands, qk + 6144, 3, mrow, g, ms, px, qoff);   // high (hh)
  __syncthreads();                                   // b2

  // ---- phase C: prefetch convM B-frags (bands stable), then attnLH -------
  half8 bfrM[4];
  #pragma unroll
  for (int ks = 0; ks < 4; ++ks){
    H8 t; int band = 1 + (ks >> 1); int cb = (ks & 1)*32 + g*8;
    #pragma unroll
    for (int k = 0; k < 8; ++k)
      t.s[k] = bands[band*2048 + (cb + k)*32 + (px ^ (g << 3))];
    bfrM[ks] = t.v;
  }
  {
    const uint16_t* qs = qk + hi5*6144;
    int aoff = (li & 1)*64 + wv*8;                   // np*64 + W*8
    attn_core<16>(qs + (li >> 1)*128 + aoff, qs + 2048 + aoff, qs + 4096 + aoff,
                  SC_LH, (uint4*)(ybuf + (hi5 ? 3 : 0)*1024 + wv*128) + li);
  }
  __syncthreads();                                   // b3

  // ---- phase D: convM (full qk), bfrM already in registers ---------------
  {
    #pragma unroll
    for (int mi = 0; mi < 6; ++mi){
      int mt = ms*6 + mi;
      f32x4 acc = {0.f,0.f,0.f,0.f};
      #pragma unroll
      for (int ks = 0; ks < 4; ++ks){
        half8 a = *(const half8*)&wM[(mt*16 + mrow)*128 + ks*32 + g*8];
        acc = __builtin_amdgcn_mfma_f32_16x16x32_f16(a, bfrM[ks], acc, 0, 0, 0);
      }
      uint16_t* wp = qk + (mt*4 + g)*128 + qoff;     // G = mt*4+g 0..95
      wp[0]  = f2h(acc[0]); wp[4]  = f2h(acc[1]);
      wp[64] = f2h(acc[2]); wp[68] = f2h(acc[3]);
    }
  }
  __syncthreads();                                   // b4

  // ---- phase E: attnM -> park y1 (band1), y2 (band2) ---------------------
  {
    int m = lane;                                    // chpair 0..63
    int aoff = (m & 1)*64 + wv*8;
    attn_core<32>(qk + (m >> 1)*128 + aoff, qk + 4096 + aoff, qk + 8192 + aoff,
                  SC_M, (uint4*)(ybuf + (m < 32 ? 1 : 2)*1024 + wv*128) + (m & 31));
  }
  __syncthreads();                                   // b5

  // ---- phase F: y readback (cross-thread) --------------------------------
  float ya[4][4];
  {
    int chi = tid & 1, m = (tid >> 1) & 31, W = tid >> 6;
    #pragma unroll
    for (int p = 0; p < 4; ++p){
      uint32_t lo = ybuf[p*1024 + W*128 + m*4 + chi*2];
      uint32_t hi_ = ybuf[p*1024 + W*128 + m*4 + chi*2 + 1];
      ya[p][0] = h2f((uint16_t)(lo & 0xffffu));
      ya[p][1] = h2f((uint16_t)(lo >> 16));
      ya[p][2] = h2f((uint16_t)(hi_ & 0xffffu));
      ya[p][3] = h2f((uint16_t)(hi_ >> 16));
    }
  }
  __syncthreads();                                   // b6

  // ---- phase G: iDWT in regs -> ot (32KB overlay) ------------------------
  {
    int chi = tid & 1, m = (tid >> 1) & 31, W = tid >> 6;
    int ch = 2*m + chi;
    float* otc = ot + ch*128 + ((W*4) ^ ((ch & 7) << 2));
    #pragma unroll
    for (int rp = 0; rp < 2; ++rp){
      float4 top, bot;
      #pragma unroll
      for (int cp = 0; cp < 2; ++cp){
        int s2 = rp*2 + cp;
        float ll = ya[0][s2], lh = ya[1][s2];
        float hl = ya[2][s2], hh = ya[3][s2];
        float va = 0.5f*(ll - lh - hl + hh);
        float vb = 0.5f*(ll - lh + hl - hh);
        float vc = 0.5f*(ll + lh - hl - hh);
        float vd = 0.5f*(ll + lh + hl + hh);
        if (cp == 0){ top.x = va; top.y = vb; bot.x = vc; bot.y = vd; }
        else        { top.z = va; top.w = vb; bot.z = vc; bot.w = vd; }
      }
      *(float4*)&otc[(2*rp)*32]   = top;
      *(float4*)&otc[(2*rp+1)*32] = bot;
    }
  }
  __syncthreads();                                   // b7

  // ---- phase H: coalesced store ------------------------------------------
  {
    int ch = tid >> 3, row = (tid >> 1) & 3, half = tid & 1;
    const float* rowp = ot + ch*128 + row*32;
    int sw = (ch & 7) << 2;
    float4 v0 = *(const float4*)&rowp[(half*16 + 0)  ^ sw];
    float4 v1 = *(const float4*)&rowp[(half*16 + 4)  ^ sw];
    float4 v2 = *(const float4*)&rowp[(half*16 + 8)  ^ sw];
    float4 v3 = *(const float4*)&rowp[(half*16 + 12) ^ sw];
    float* dst = out + (((size_t)b*64 + ch)*256 + (size_t)(4*hw + row))*256
               + col0 + half*16;
    ((float4*)dst)[0] = v0; ((float4*)dst)[1] = v1;
    ((float4*)dst)[2] = v2; ((float4*)dst)[3] = v3;
  }
}

// ---------------------------------------------------------------------------
extern "C" void kernel_launch(void* const* d_in, const int* in_sizes, int n_in,
                              void* d_out, int out_size, void* d_ws, size_t ws_size,
                              hipStream_t stream){
  const float* x   = (const float*)d_in[0];
  const float* wlh = (const float*)d_in[1];
  const float* wm  = (const float*)d_in[2];
  float* out = (float*)d_out;
  halfT* wHp = (halfT*)d_ws;               // 61440 f16 = 122880 B

  hipLaunchKernelGGL(k_wt,    dim3(240),  dim3(256), 0, stream, wlh, wm, wHp);
  hipLaunchKernelGGL(k_fused, dim3(4096), dim3(512), 0, stream, x, wHp, out);
}